// Round 7
// baseline (257.740 us; speedup 1.0000x reference)
//
#include <hip/hip_runtime.h>
#include <math.h>

constexpr int NNODES = 80000;
constexpr int NEDGES = 1280000;

typedef __attribute__((ext_vector_type(8))) short bf16x8;
typedef __attribute__((ext_vector_type(4))) float f32x4;
typedef __attribute__((ext_vector_type(4))) int i32x4;
typedef __attribute__((ext_vector_type(2))) unsigned u32x2;

__device__ __forceinline__ short f2b(float f) {
    unsigned u = __builtin_bit_cast(unsigned, f);
    u = u + 0x7FFFu + ((u >> 16) & 1u);          // RNE to bf16
    return (short)(u >> 16);
}
__device__ __forceinline__ unsigned pk2(float lo, float hi) {
    return ((unsigned)(unsigned short)f2b(hi) << 16) | (unsigned)(unsigned short)f2b(lo);
}
__device__ __forceinline__ float blo(unsigned u) { return __builtin_bit_cast(float, u << 16); }
__device__ __forceinline__ float bhi(unsigned u) { return __builtin_bit_cast(float, u & 0xFFFF0000u); }

// K0: fold W3/b3 through Wh; emit per-lane A-fragments for 16x16x32 MFMA.
// A-frag at lane l: A[row = l&15][k = 8*(l>>4) + i], i=0..7.
__global__ void k_pre(const float* __restrict__ W3, const float* __restrict__ b3,
                      const float* __restrict__ Wh, const float* __restrict__ bh,
                      const float* __restrict__ Wo,
                      short* __restrict__ W35F, short* __restrict__ WoF,
                      float* __restrict__ c) {
    int t = threadIdx.x;            // 1024 threads
#pragma unroll
    for (int r = 0; r < 2; ++r) {
        int idx = r * 1024 + t;
        int m = idx >> 9, l = (idx >> 3) & 63, i = idx & 7;
        int k = 8 * (l >> 4) + i;
        int ch = 16 * m + (l & 15);
        float s = 0.f;
        if (k < 16) {
#pragma unroll
            for (int mm = 0; mm < 64; ++mm) s += Wh[ch * 64 + mm] * W3[mm * 16 + k];
        }
        W35F[idx] = f2b(s);
    }
#pragma unroll
    for (int r = 0; r < 4; ++r) {
        int idx = r * 1024 + t;
        int f = idx >> 9, l = (idx >> 3) & 63, i = idx & 7;
        int ch = 16 * (f >> 1) + (l & 15);
        int k = 32 * (f & 1) + 8 * (l >> 4) + i;
        WoF[idx] = f2b(Wo[ch * 64 + k]);
    }
    if (t < 64) {
        float cc = bh[t];
#pragma unroll
        for (int m = 0; m < 64; ++m) cc += Wh[t * 64 + m] * b3[m];
        c[t] = cc;
    }
}

// K1: per-node  n2' = (h@W1^T + b1 + e@W2^T + b2) @ Wh^T + 0.5*c
// Output: bf16, PERMUTED per-lane-gather layout:
//   n2b[node][pos], pos = (r>>2)*16 + (lane>>4)*4 + (r&3),  r = lane&15
// so that k_edge's lane (e,g) reads its 16 channels {16M+4g+j} as 32 contiguous bytes.
__global__ __launch_bounds__(256) void k_node(
    const float* __restrict__ h, const float* __restrict__ e,
    const float* __restrict__ W1, const float* __restrict__ b1,
    const float* __restrict__ W2, const float* __restrict__ b2,
    const float* __restrict__ Wh, const float* __restrict__ c,
    short* __restrict__ n2b) {
    __shared__ float sW1T[64 * 65];
    __shared__ float sW2T[32 * 65];
    __shared__ float sWhT[64 * 65];
    __shared__ float sStage[4][160];

    int tid = threadIdx.x;
    for (int idx = tid; idx < 64 * 64; idx += 256) {
        int j = idx >> 6, k = idx & 63;
        sW1T[k * 65 + j] = W1[idx];
        sWhT[k * 65 + j] = Wh[idx];
    }
    for (int idx = tid; idx < 64 * 32; idx += 256) {
        int j = idx >> 5, k = idx & 31;
        sW2T[k * 65 + j] = W2[idx];
    }
    __syncthreads();

    int w = tid >> 6, lane = tid & 63;
    float* hs = &sStage[w][0];
    float* es = &sStage[w][64];
    float* ns = &sStage[w][96];
    int waveId = blockIdx.x * 4 + w;
    float bb = b1[lane] + b2[lane];
    float chalf = 0.5f * c[lane];
    int rr = lane & 15;
    int pos = (rr >> 2) * 16 + (lane >> 4) * 4 + (rr & 3);

    for (int i = 0; i < 20; ++i) {
        int n = waveId * 20 + i;
        hs[lane] = h[n * 64 + lane];
        if (lane < 32) es[lane] = e[n * 32 + lane];
        float a = bb;
#pragma unroll
        for (int k = 0; k < 64; ++k) a += hs[k] * sW1T[k * 65 + lane];
#pragma unroll
        for (int k = 0; k < 32; ++k) a += es[k] * sW2T[k * 65 + lane];
        ns[lane] = a;
        float o = chalf;
#pragma unroll
        for (int k = 0; k < 64; ++k) o += ns[k] * sWhT[k * 65 + lane];
        n2b[n * 64 + pos] = f2b(o);
    }
}

// K2: 16-edge tiles, 16x16x32 MFMA, software-pipelined; bf16 n2 gathers
// (2x16B contiguous per lane), single-read eij (g<2 lanes only), NT stream loads.
__global__ __launch_bounds__(256, 3) void k_edge(
    const float* __restrict__ eij, const int* __restrict__ src, const int* __restrict__ dst,
    const short* __restrict__ n2b, const short* __restrict__ W35F, const short* __restrict__ WoF,
    const float* __restrict__ bo, float* __restrict__ out) {
    __shared__ __align__(16) short sWoF[4096];       // 8 KB: [f][lane][i]
    __shared__ __align__(16) unsigned shm[4][576];   // per-wave hm redistribution

    int tid = threadIdx.x, w = tid >> 6, lane = tid & 63;
    int e = lane & 15, g = lane >> 4;

    for (int idx = tid; idx < 512; idx += 256)
        ((ulonglong2*)sWoF)[idx] = ((const ulonglong2*)WoF)[idx];
    __syncthreads();

    bf16x8 w35[4];
#pragma unroll
    for (int m = 0; m < 4; ++m)
        w35[m] = *(const bf16x8*)(W35F + (m * 64 + lane) * 8);
    f32x4 boA[4];
#pragma unroll
    for (int m2 = 0; m2 < 4; ++m2)
        boA[m2] = *(const f32x4*)(bo + 16 * m2 + 4 * g);

    unsigned* hw = shm[w];
    const bool glow = (g < 2);
    const int eoff = (g & 1) * 8;

    int gw = blockIdx.x * 4 + w;        // 0..9999
    int base = gw * 128;                // 8 tiles * 16 edges

    int sv[3], dv[3];
    f32x4 ev0[2], ev1[2];
    i32x4 sA[2], sB[2], dA[2], dB[2];

    const f32x4 z4 = {0.f, 0.f, 0.f, 0.f};
    ev0[0] = z4; ev0[1] = z4; ev1[0] = z4; ev1[1] = z4;

    // prologue
    sv[0] = __builtin_nontemporal_load(src + base + e);
    dv[0] = __builtin_nontemporal_load(dst + base + e);
    sv[1] = __builtin_nontemporal_load(src + base + 16 + e);
    dv[1] = __builtin_nontemporal_load(dst + base + 16 + e);
    if (glow) {
        ev0[0] = __builtin_nontemporal_load((const f32x4*)(eij + (size_t)(base + e) * 16 + eoff));
        ev1[0] = __builtin_nontemporal_load((const f32x4*)(eij + (size_t)(base + e) * 16 + eoff + 4));
    }
    {
        const short* ps = n2b + (size_t)sv[0] * 64 + g * 16;
        const short* pd = n2b + (size_t)dv[0] * 64 + g * 16;
        sA[0] = *(const i32x4*)ps;  sB[0] = *(const i32x4*)(ps + 8);
        dA[0] = *(const i32x4*)pd;  dB[0] = *(const i32x4*)(pd + 8);
    }

#pragma unroll
    for (int t = 0; t < 8; ++t) {
        const int cur = t & 1, nxt = cur ^ 1;

        // idx prefetch for t+2
        if (t < 6) {
            int r = base + (t + 2) * 16 + e;
            sv[(t + 2) % 3] = __builtin_nontemporal_load(src + r);
            dv[(t + 2) % 3] = __builtin_nontemporal_load(dst + r);
        }
        // n2 gathers + eij for t+1
        if (t < 7) {
            const short* ps = n2b + (size_t)sv[(t + 1) % 3] * 64 + g * 16;
            const short* pd = n2b + (size_t)dv[(t + 1) % 3] * 64 + g * 16;
            sA[nxt] = *(const i32x4*)ps;  sB[nxt] = *(const i32x4*)(ps + 8);
            dA[nxt] = *(const i32x4*)pd;  dB[nxt] = *(const i32x4*)(pd + 8);
            if (glow) {
                int r = base + (t + 1) * 16 + e;
                ev0[nxt] = __builtin_nontemporal_load((const f32x4*)(eij + (size_t)r * 16 + eoff));
                ev1[nxt] = __builtin_nontemporal_load((const f32x4*)(eij + (size_t)r * 16 + eoff + 4));
            }
        }

        // compute tile t
        int erow = base + t * 16 + e;
        i32x4 ebi;
        ebi[0] = (int)pk2(ev0[cur][0], ev0[cur][1]);
        ebi[1] = (int)pk2(ev0[cur][2], ev0[cur][3]);
        ebi[2] = (int)pk2(ev1[cur][0], ev1[cur][1]);
        ebi[3] = (int)pk2(ev1[cur][2], ev1[cur][3]);
        bf16x8 eb = __builtin_bit_cast(bf16x8, ebi);

#define L1(M, US, UD, PB)                                                          \
        {                                                                          \
            f32x4 P = __builtin_amdgcn_mfma_f32_16x16x32_bf16(w35[M], eb, z4, 0, 0, 0); \
            unsigned us0 = (unsigned)US[cur][PB], us1 = (unsigned)US[cur][PB + 1]; \
            unsigned ud0 = (unsigned)UD[cur][PB], ud1 = (unsigned)UD[cur][PB + 1]; \
            float h0 = P[0] + blo(us0) + blo(ud0);                                 \
            float h1 = P[1] + bhi(us0) + bhi(ud0);                                 \
            float h2 = P[2] + blo(us1) + blo(ud1);                                 \
            float h3 = P[3] + bhi(us1) + bhi(ud1);                                 \
            h0 = h0 > 0.f ? h0 : __expf(h0) - 1.f;                                 \
            h1 = h1 > 0.f ? h1 : __expf(h1) - 1.f;                                 \
            h2 = h2 > 0.f ? h2 : __expf(h2) - 1.f;                                 \
            h3 = h3 > 0.f ? h3 : __expf(h3) - 1.f;                                 \
            u32x2 uu; uu[0] = pk2(h0, h1); uu[1] = pk2(h2, h3);                    \
            *(u32x2*)(&hw[e * 36 + 8 * M + 2 * g]) = uu;                           \
        }
        L1(0, sA, dA, 0)
        L1(1, sA, dA, 2)
        L1(2, sB, dB, 0)
        L1(3, sB, dB, 2)
#undef L1
        asm volatile("" ::: "memory");      // LDS writes before frag reads

        i32x4 hf0 = *(const i32x4*)(&hw[e * 36 + 4 * g]);        // ks=0: k=8g+i
        i32x4 hf1 = *(const i32x4*)(&hw[e * 36 + 16 + 4 * g]);   // ks=1: k=32+8g+i
        bf16x8 B0 = __builtin_bit_cast(bf16x8, hf0);
        bf16x8 B1 = __builtin_bit_cast(bf16x8, hf1);

#define L2(M2)                                                                     \
        {                                                                          \
            bf16x8 A0 = *(const bf16x8*)(sWoF + ((M2 * 2 + 0) * 64 + lane) * 8);   \
            bf16x8 A1 = *(const bf16x8*)(sWoF + ((M2 * 2 + 1) * 64 + lane) * 8);   \
            f32x4 o = __builtin_amdgcn_mfma_f32_16x16x32_bf16(A0, B0, boA[M2], 0, 0, 0); \
            o = __builtin_amdgcn_mfma_f32_16x16x32_bf16(A1, B1, o, 0, 0, 0);       \
            __builtin_nontemporal_store(o, (f32x4*)(out + (size_t)erow * 64 + 16 * M2 + 4 * g)); \
        }
        L2(0)
        L2(1)
        L2(2)
        L2(3)
#undef L2
        asm volatile("" ::: "memory");      // frag reads done before next tile's writes
    }
}

extern "C" void kernel_launch(void* const* d_in, const int* in_sizes, int n_in,
                              void* d_out, int out_size, void* d_ws, size_t ws_size,
                              hipStream_t stream) {
    const float* h   = (const float*)d_in[0];
    const float* e   = (const float*)d_in[1];
    const float* eij = (const float*)d_in[2];
    const int*   src = (const int*)d_in[3];
    const int*   dst = (const int*)d_in[4];
    const float* W1  = (const float*)d_in[5];
    const float* b1  = (const float*)d_in[6];
    const float* W2  = (const float*)d_in[7];
    const float* b2  = (const float*)d_in[8];
    const float* W3  = (const float*)d_in[9];
    const float* b3  = (const float*)d_in[10];
    const float* Wh  = (const float*)d_in[11];
    const float* bh  = (const float*)d_in[12];
    const float* Wo  = (const float*)d_in[13];
    const float* bo  = (const float*)d_in[14];
    float* out = (float*)d_out;

    short* n2b  = (short*)d_ws;                        // 80000*64 bf16 = 10.24 MB
    short* W35F = n2b + (size_t)NNODES * 64;           // 2048 bf16 (A-frag order)
    short* WoF  = W35F + 2048;                         // 4096 bf16 (A-frag order)
    float* c    = (float*)(WoF + 4096);                // 64 f32

    hipLaunchKernelGGL(k_pre, dim3(1), dim3(1024), 0, stream, W3, b3, Wh, bh, Wo, W35F, WoF, c);
    hipLaunchKernelGGL(k_node, dim3(1000), dim3(256), 0, stream,
                       h, e, W1, b1, W2, b2, Wh, c, n2b);
    // 2500 blocks * 4 waves * 8 tiles * 16 edges = 1,280,000
    hipLaunchKernelGGL(k_edge, dim3(2500), dim3(256), 0, stream,
                       eij, src, dst, n2b, W35F, WoF, bo, out);
}

// Round 8
// 249.308 us; speedup vs baseline: 1.0338x; 1.0338x over previous
//
#include <hip/hip_runtime.h>
#include <math.h>

constexpr int NNODES = 80000;
constexpr int NEDGES = 1280000;

typedef __attribute__((ext_vector_type(8))) short bf16x8;
typedef __attribute__((ext_vector_type(4))) float f32x4;
typedef __attribute__((ext_vector_type(4))) int i32x4;
typedef __attribute__((ext_vector_type(2))) unsigned u32x2;

__device__ __forceinline__ short f2b(float f) {
    unsigned u = __builtin_bit_cast(unsigned, f);
    u = u + 0x7FFFu + ((u >> 16) & 1u);          // RNE to bf16
    return (short)(u >> 16);
}
__device__ __forceinline__ unsigned pk2(float lo, float hi) {
    return ((unsigned)(unsigned short)f2b(hi) << 16) | (unsigned)(unsigned short)f2b(lo);
}
__device__ __forceinline__ float blo(unsigned u) { return __builtin_bit_cast(float, u << 16); }
__device__ __forceinline__ float bhi(unsigned u) { return __builtin_bit_cast(float, u & 0xFFFF0000u); }

// K0: fold W3/b3 through Wh; emit per-lane A-fragments for 16x16x32 MFMA.
// A-frag at lane l: A[row = l&15][k = 8*(l>>4) + i], i=0..7.
__global__ void k_pre(const float* __restrict__ W3, const float* __restrict__ b3,
                      const float* __restrict__ Wh, const float* __restrict__ bh,
                      const float* __restrict__ Wo,
                      short* __restrict__ W35F, short* __restrict__ WoF,
                      float* __restrict__ c) {
    int t = threadIdx.x;            // 1024 threads
#pragma unroll
    for (int r = 0; r < 2; ++r) {
        int idx = r * 1024 + t;
        int m = idx >> 9, l = (idx >> 3) & 63, i = idx & 7;
        int k = 8 * (l >> 4) + i;
        int ch = 16 * m + (l & 15);
        float s = 0.f;
        if (k < 16) {
#pragma unroll
            for (int mm = 0; mm < 64; ++mm) s += Wh[ch * 64 + mm] * W3[mm * 16 + k];
        }
        W35F[idx] = f2b(s);
    }
#pragma unroll
    for (int r = 0; r < 4; ++r) {
        int idx = r * 1024 + t;
        int f = idx >> 9, l = (idx >> 3) & 63, i = idx & 7;
        int ch = 16 * (f >> 1) + (l & 15);
        int k = 32 * (f & 1) + 8 * (l >> 4) + i;
        WoF[idx] = f2b(Wo[ch * 64 + k]);
    }
    if (t < 64) {
        float cc = bh[t];
#pragma unroll
        for (int m = 0; m < 64; ++m) cc += Wh[t * 64 + m] * b3[m];
        c[t] = cc;
    }
}

// K1: per-node  n2' = (h@W1^T + b1 + e@W2^T + b2) @ Wh^T + 0.5*c
// Output bf16, permuted so k_edge lane (e,g) reads its 16 channels contiguously.
__global__ __launch_bounds__(256) void k_node(
    const float* __restrict__ h, const float* __restrict__ e,
    const float* __restrict__ W1, const float* __restrict__ b1,
    const float* __restrict__ W2, const float* __restrict__ b2,
    const float* __restrict__ Wh, const float* __restrict__ c,
    short* __restrict__ n2b) {
    __shared__ float sW1T[64 * 65];
    __shared__ float sW2T[32 * 65];
    __shared__ float sWhT[64 * 65];
    __shared__ float sStage[4][160];

    int tid = threadIdx.x;
    for (int idx = tid; idx < 64 * 64; idx += 256) {
        int j = idx >> 6, k = idx & 63;
        sW1T[k * 65 + j] = W1[idx];
        sWhT[k * 65 + j] = Wh[idx];
    }
    for (int idx = tid; idx < 64 * 32; idx += 256) {
        int j = idx >> 5, k = idx & 31;
        sW2T[k * 65 + j] = W2[idx];
    }
    __syncthreads();

    int w = tid >> 6, lane = tid & 63;
    float* hs = &sStage[w][0];
    float* es = &sStage[w][64];
    float* ns = &sStage[w][96];
    int waveId = blockIdx.x * 4 + w;
    float bb = b1[lane] + b2[lane];
    float chalf = 0.5f * c[lane];
    int rr = lane & 15;
    int pos = (rr >> 2) * 16 + (lane >> 4) * 4 + (rr & 3);

    for (int i = 0; i < 20; ++i) {
        int n = waveId * 20 + i;
        hs[lane] = h[n * 64 + lane];
        if (lane < 32) es[lane] = e[n * 32 + lane];
        float a = bb;
#pragma unroll
        for (int k = 0; k < 64; ++k) a += hs[k] * sW1T[k * 65 + lane];
#pragma unroll
        for (int k = 0; k < 32; ++k) a += es[k] * sW2T[k * 65 + lane];
        ns[lane] = a;
        float o = chalf;
#pragma unroll
        for (int k = 0; k < 64; ++k) o += ns[k] * sWhT[k * 65 + lane];
        n2b[n * 64 + pos] = f2b(o);
    }
}

// K2: TLP probe. 4 tiles/wave (5000 blocks), all idx preloaded, bo in LDS,
// depth-1 gather dbuf, VGPR cap 128 (4 waves/EU min).
__global__ __launch_bounds__(256, 4) void k_edge(
    const float* __restrict__ eij, const int* __restrict__ src, const int* __restrict__ dst,
    const short* __restrict__ n2b, const short* __restrict__ W35F, const short* __restrict__ WoF,
    const float* __restrict__ bo, float* __restrict__ out) {
    __shared__ __align__(16) short sWoF[4096];       // 8 KB: [f][lane][i]
    __shared__ __align__(16) unsigned shm[4][576];   // per-wave hm redistribution
    __shared__ __align__(16) float sbo[64];

    int tid = threadIdx.x, w = tid >> 6, lane = tid & 63;
    int e = lane & 15, g = lane >> 4;

    for (int idx = tid; idx < 512; idx += 256)
        ((ulonglong2*)sWoF)[idx] = ((const ulonglong2*)WoF)[idx];
    if (tid < 64) sbo[tid] = bo[tid];
    __syncthreads();

    bf16x8 w35[4];
#pragma unroll
    for (int m = 0; m < 4; ++m)
        w35[m] = *(const bf16x8*)(W35F + (m * 64 + lane) * 8);

    unsigned* hw = shm[w];
    const bool glow = (g < 2);
    const int eoff = (g & 1) * 8;
    const f32x4 z4 = {0.f, 0.f, 0.f, 0.f};

    int gw = blockIdx.x * 4 + w;        // 0..19999
    int base = gw * 64;                 // 4 tiles * 16 edges

    // all idx up front (kills the idx->gather serial chain)
    int sv[4], dv[4];
#pragma unroll
    for (int t = 0; t < 4; ++t) {
        sv[t] = __builtin_nontemporal_load(src + base + t * 16 + e);
        dv[t] = __builtin_nontemporal_load(dst + base + t * 16 + e);
    }

    f32x4 ev0[2], ev1[2];
    i32x4 nsA[2], nsB[2], ndA[2], ndB[2];
    ev0[0] = z4; ev0[1] = z4; ev1[0] = z4; ev1[1] = z4;

    if (glow) {
        ev0[0] = __builtin_nontemporal_load((const f32x4*)(eij + (size_t)(base + e) * 16 + eoff));
        ev1[0] = __builtin_nontemporal_load((const f32x4*)(eij + (size_t)(base + e) * 16 + eoff + 4));
    }
    {
        const short* ps = n2b + (size_t)sv[0] * 64 + g * 16;
        const short* pd = n2b + (size_t)dv[0] * 64 + g * 16;
        nsA[0] = *(const i32x4*)ps;  nsB[0] = *(const i32x4*)(ps + 8);
        ndA[0] = *(const i32x4*)pd;  ndB[0] = *(const i32x4*)(pd + 8);
    }

#pragma unroll
    for (int t = 0; t < 4; ++t) {
        const int cur = t & 1, nxt = cur ^ 1;

        if (t < 3) {
            const short* ps = n2b + (size_t)sv[t + 1] * 64 + g * 16;
            const short* pd = n2b + (size_t)dv[t + 1] * 64 + g * 16;
            nsA[nxt] = *(const i32x4*)ps;  nsB[nxt] = *(const i32x4*)(ps + 8);
            ndA[nxt] = *(const i32x4*)pd;  ndB[nxt] = *(const i32x4*)(pd + 8);
            if (glow) {
                int r = base + (t + 1) * 16 + e;
                ev0[nxt] = __builtin_nontemporal_load((const f32x4*)(eij + (size_t)r * 16 + eoff));
                ev1[nxt] = __builtin_nontemporal_load((const f32x4*)(eij + (size_t)r * 16 + eoff + 4));
            }
        }

        int erow = base + t * 16 + e;
        i32x4 ebi;
        ebi[0] = (int)pk2(ev0[cur][0], ev0[cur][1]);
        ebi[1] = (int)pk2(ev0[cur][2], ev0[cur][3]);
        ebi[2] = (int)pk2(ev1[cur][0], ev1[cur][1]);
        ebi[3] = (int)pk2(ev1[cur][2], ev1[cur][3]);
        bf16x8 eb = __builtin_bit_cast(bf16x8, ebi);

#define L1(M, US, UD, PB)                                                          \
        {                                                                          \
            f32x4 P = __builtin_amdgcn_mfma_f32_16x16x32_bf16(w35[M], eb, z4, 0, 0, 0); \
            unsigned us0 = (unsigned)US[cur][PB], us1 = (unsigned)US[cur][PB + 1]; \
            unsigned ud0 = (unsigned)UD[cur][PB], ud1 = (unsigned)UD[cur][PB + 1]; \
            float h0 = P[0] + blo(us0) + blo(ud0);                                 \
            float h1 = P[1] + bhi(us0) + bhi(ud0);                                 \
            float h2 = P[2] + blo(us1) + blo(ud1);                                 \
            float h3 = P[3] + bhi(us1) + bhi(ud1);                                 \
            h0 = h0 > 0.f ? h0 : __expf(h0) - 1.f;                                 \
            h1 = h1 > 0.f ? h1 : __expf(h1) - 1.f;                                 \
            h2 = h2 > 0.f ? h2 : __expf(h2) - 1.f;                                 \
            h3 = h3 > 0.f ? h3 : __expf(h3) - 1.f;                                 \
            u32x2 uu; uu[0] = pk2(h0, h1); uu[1] = pk2(h2, h3);                    \
            *(u32x2*)(&hw[e * 36 + 8 * M + 2 * g]) = uu;                           \
        }
        L1(0, nsA, ndA, 0)
        L1(1, nsA, ndA, 2)
        L1(2, nsB, ndB, 0)
        L1(3, nsB, ndB, 2)
#undef L1
        asm volatile("" ::: "memory");      // LDS writes before frag reads

        i32x4 hf0 = *(const i32x4*)(&hw[e * 36 + 4 * g]);        // ks=0: k=8g+i
        i32x4 hf1 = *(const i32x4*)(&hw[e * 36 + 16 + 4 * g]);   // ks=1: k=32+8g+i
        bf16x8 B0 = __builtin_bit_cast(bf16x8, hf0);
        bf16x8 B1 = __builtin_bit_cast(bf16x8, hf1);

#define L2(M2)                                                                     \
        {                                                                          \
            bf16x8 A0 = *(const bf16x8*)(sWoF + ((M2 * 2 + 0) * 64 + lane) * 8);   \
            bf16x8 A1 = *(const bf16x8*)(sWoF + ((M2 * 2 + 1) * 64 + lane) * 8);   \
            f32x4 cb = *(const f32x4*)(sbo + 16 * M2 + 4 * g);                     \
            f32x4 o = __builtin_amdgcn_mfma_f32_16x16x32_bf16(A0, B0, cb, 0, 0, 0); \
            o = __builtin_amdgcn_mfma_f32_16x16x32_bf16(A1, B1, o, 0, 0, 0);       \
            __builtin_nontemporal_store(o, (f32x4*)(out + (size_t)erow * 64 + 16 * M2 + 4 * g)); \
        }
        L2(0)
        L2(1)
        L2(2)
        L2(3)
#undef L2
        asm volatile("" ::: "memory");      // frag reads done before next tile's writes
    }
}

extern "C" void kernel_launch(void* const* d_in, const int* in_sizes, int n_in,
                              void* d_out, int out_size, void* d_ws, size_t ws_size,
                              hipStream_t stream) {
    const float* h   = (const float*)d_in[0];
    const float* e   = (const float*)d_in[1];
    const float* eij = (const float*)d_in[2];
    const int*   src = (const int*)d_in[3];
    const int*   dst = (const int*)d_in[4];
    const float* W1  = (const float*)d_in[5];
    const float* b1  = (const float*)d_in[6];
    const float* W2  = (const float*)d_in[7];
    const float* b2  = (const float*)d_in[8];
    const float* W3  = (const float*)d_in[9];
    const float* b3  = (const float*)d_in[10];
    const float* Wh  = (const float*)d_in[11];
    const float* bh  = (const float*)d_in[12];
    const float* Wo  = (const float*)d_in[13];
    const float* bo  = (const float*)d_in[14];
    float* out = (float*)d_out;

    short* n2b  = (short*)d_ws;                        // 80000*64 bf16 = 10.24 MB
    short* W35F = n2b + (size_t)NNODES * 64;           // 2048 bf16 (A-frag order)
    short* WoF  = W35F + 2048;                         // 4096 bf16 (A-frag order)
    float* c    = (float*)(WoF + 4096);                // 64 f32

    hipLaunchKernelGGL(k_pre, dim3(1), dim3(1024), 0, stream, W3, b3, Wh, bh, Wo, W35F, WoF, c);
    hipLaunchKernelGGL(k_node, dim3(1000), dim3(256), 0, stream,
                       h, e, W1, b1, W2, b2, Wh, c, n2b);
    // 5000 blocks * 4 waves * 4 tiles * 16 edges = 1,280,000
    hipLaunchKernelGGL(k_edge, dim3(5000), dim3(256), 0, stream,
                       eij, src, dst, n2b, W35F, WoF, bo, out);
}

// Round 9
// 242.483 us; speedup vs baseline: 1.0629x; 1.0281x over previous
//
#include <hip/hip_runtime.h>
#include <math.h>

constexpr int NNODES = 80000;
constexpr int NEDGES = 1280000;

typedef __attribute__((ext_vector_type(8))) short bf16x8;
typedef __attribute__((ext_vector_type(4))) float f32x4;
typedef __attribute__((ext_vector_type(4))) int i32x4;
typedef __attribute__((ext_vector_type(2))) unsigned u32x2;

__device__ __forceinline__ short f2b(float f) {
    unsigned u = __builtin_bit_cast(unsigned, f);
    u = u + 0x7FFFu + ((u >> 16) & 1u);          // RNE to bf16
    return (short)(u >> 16);
}
__device__ __forceinline__ unsigned pk2(float lo, float hi) {
    return ((unsigned)(unsigned short)f2b(hi) << 16) | (unsigned)(unsigned short)f2b(lo);
}
__device__ __forceinline__ float blo(unsigned u) { return __builtin_bit_cast(float, u << 16); }
__device__ __forceinline__ float bhi(unsigned u) { return __builtin_bit_cast(float, u & 0xFFFF0000u); }

// K0: fold W3/b3 through Wh; emit per-lane fragments for 16x16x32 MFMA.
// frag at lane l, elem i: W[16*blk + (l&15)][8*(l>>4) + i (+32*kk for Wo)]
__global__ void k_pre(const float* __restrict__ W3, const float* __restrict__ b3,
                      const float* __restrict__ Wh, const float* __restrict__ bh,
                      const float* __restrict__ Wo,
                      short* __restrict__ W35F, short* __restrict__ WoF,
                      float* __restrict__ c) {
    int t = threadIdx.x;            // 1024 threads
#pragma unroll
    for (int r = 0; r < 2; ++r) {
        int idx = r * 1024 + t;
        int m = idx >> 9, l = (idx >> 3) & 63, i = idx & 7;
        int k = 8 * (l >> 4) + i;
        int ch = 16 * m + (l & 15);
        float s = 0.f;
        if (k < 16) {
#pragma unroll
            for (int mm = 0; mm < 64; ++mm) s += Wh[ch * 64 + mm] * W3[mm * 16 + k];
        }
        W35F[idx] = f2b(s);
    }
#pragma unroll
    for (int r = 0; r < 4; ++r) {
        int idx = r * 1024 + t;
        int f = idx >> 9, l = (idx >> 3) & 63, i = idx & 7;
        int ch = 16 * (f >> 1) + (l & 15);
        int k = 32 * (f & 1) + 8 * (l >> 4) + i;
        WoF[idx] = f2b(Wo[ch * 64 + k]);
    }
    if (t < 64) {
        float cc = bh[t];
#pragma unroll
        for (int m = 0; m < 64; ++m) cc += Wh[t * 64 + m] * b3[m];
        c[t] = cc;
    }
}

// K1: per-node  n2' = (h@W1^T + b1 + e@W2^T + b2) @ Wh^T + 0.5*c,  bf16 PLAIN rows.
__global__ __launch_bounds__(256) void k_node(
    const float* __restrict__ h, const float* __restrict__ e,
    const float* __restrict__ W1, const float* __restrict__ b1,
    const float* __restrict__ W2, const float* __restrict__ b2,
    const float* __restrict__ Wh, const float* __restrict__ c,
    short* __restrict__ n2b) {
    __shared__ float sW1T[64 * 65];
    __shared__ float sW2T[32 * 65];
    __shared__ float sWhT[64 * 65];
    __shared__ float sStage[4][160];

    int tid = threadIdx.x;
    for (int idx = tid; idx < 64 * 64; idx += 256) {
        int j = idx >> 6, k = idx & 63;
        sW1T[k * 65 + j] = W1[idx];
        sWhT[k * 65 + j] = Wh[idx];
    }
    for (int idx = tid; idx < 64 * 32; idx += 256) {
        int j = idx >> 5, k = idx & 31;
        sW2T[k * 65 + j] = W2[idx];
    }
    __syncthreads();

    int w = tid >> 6, lane = tid & 63;
    float* hs = &sStage[w][0];
    float* es = &sStage[w][64];
    float* ns = &sStage[w][96];
    int waveId = blockIdx.x * 4 + w;
    float bb = b1[lane] + b2[lane];
    float chalf = 0.5f * c[lane];

    for (int i = 0; i < 20; ++i) {
        int n = waveId * 20 + i;
        hs[lane] = h[n * 64 + lane];
        if (lane < 32) es[lane] = e[n * 32 + lane];
        float a = bb;
#pragma unroll
        for (int k = 0; k < 64; ++k) a += hs[k] * sW1T[k * 65 + lane];
#pragma unroll
        for (int k = 0; k < 32; ++k) a += es[k] * sW2T[k * 65 + lane];
        ns[lane] = a;
        float o = chalf;
#pragma unroll
        for (int k = 0; k < 64; ++k) o += ns[k] * sWhT[k * 65 + lane];
        n2b[n * 64 + lane] = f2b(o);
    }
}

// K2: all global traffic adjacent-lane-coalesced; lane-role transpose via LDS.
//   staging role: lane = (pe = l>>2 edge, pp = l&3 quarter)  -> quads read/write
//   full contiguous 64B segments of node rows / eij rows / out rows.
//   MFMA role:    lane = (e = l&15, g = l>>4), D1[ch][edge], D2[edge][ch].
__global__ __launch_bounds__(256, 4) void k_edge(
    const float* __restrict__ eij, const int* __restrict__ src, const int* __restrict__ dst,
    const short* __restrict__ n2b, const short* __restrict__ W35F, const short* __restrict__ WoF,
    const float* __restrict__ bo, float* __restrict__ out) {
    __shared__ __align__(16) short sWoF[4096];        // 8 KB
    __shared__ __align__(16) float sg[4][16 * 68];    // summed n2 rows, f32
    __shared__ __align__(16) float sej[4][16 * 20];   // eij tile, f32
    __shared__ __align__(16) unsigned shw[4][576];    // hm redistribution

    int tid = threadIdx.x, w = tid >> 6, lane = tid & 63;
    int e = lane & 15, g = lane >> 4;
    int pe = lane >> 2, pp = lane & 3;

    for (int idx = tid; idx < 512; idx += 256)
        ((ulonglong2*)sWoF)[idx] = ((const ulonglong2*)WoF)[idx];
    __syncthreads();

    bf16x8 w35[4];
#pragma unroll
    for (int m = 0; m < 4; ++m)
        w35[m] = *(const bf16x8*)(W35F + (m * 64 + lane) * 8);
    float boc[4];
#pragma unroll
    for (int M = 0; M < 4; ++M) boc[M] = bo[16 * M + e];

    float* gw_ = sg[w];
    float* ejs = sej[w];
    unsigned* hw = shw[w];
    const bool glow = (g < 2);
    const f32x4 z4 = {0.f, 0.f, 0.f, 0.f};

    int base = (blockIdx.x * 4 + w) * 128;   // 8 tiles * 16 edges

    int sv[8], dv[8];
#pragma unroll
    for (int t = 0; t < 8; ++t) {
        sv[t] = __builtin_nontemporal_load(src + base + t * 16 + pe);
        dv[t] = __builtin_nontemporal_load(dst + base + t * 16 + pe);
    }

    i32x4 sgA, sgB, dgA, dgB;     // staged node-row slices (quad-contiguous)
    f32x4 ejr;                    // staged eij slice
    {
        const short* ps = n2b + (size_t)sv[0] * 64;
        const short* pd = n2b + (size_t)dv[0] * 64;
        sgA = *(const i32x4*)(ps + pp * 8);
        sgB = *(const i32x4*)(ps + 32 + pp * 8);
        dgA = *(const i32x4*)(pd + pp * 8);
        dgB = *(const i32x4*)(pd + 32 + pp * 8);
        ejr = __builtin_nontemporal_load((const f32x4*)(eij + (size_t)(base + pe) * 16 + pp * 4));
    }

#pragma unroll
    for (int t = 0; t < 8; ++t) {
        // A: unpack+sum staged rows, write LDS (writer holds ch 8pp..+7 and 32+8pp..+7)
        f32x4 fA0, fA1, fB0, fB1;
        fA0[0] = blo((unsigned)sgA[0]) + blo((unsigned)dgA[0]);
        fA0[1] = bhi((unsigned)sgA[0]) + bhi((unsigned)dgA[0]);
        fA0[2] = blo((unsigned)sgA[1]) + blo((unsigned)dgA[1]);
        fA0[3] = bhi((unsigned)sgA[1]) + bhi((unsigned)dgA[1]);
        fA1[0] = blo((unsigned)sgA[2]) + blo((unsigned)dgA[2]);
        fA1[1] = bhi((unsigned)sgA[2]) + bhi((unsigned)dgA[2]);
        fA1[2] = blo((unsigned)sgA[3]) + blo((unsigned)dgA[3]);
        fA1[3] = bhi((unsigned)sgA[3]) + bhi((unsigned)dgA[3]);
        fB0[0] = blo((unsigned)sgB[0]) + blo((unsigned)dgB[0]);
        fB0[1] = bhi((unsigned)sgB[0]) + bhi((unsigned)dgB[0]);
        fB0[2] = blo((unsigned)sgB[1]) + blo((unsigned)dgB[1]);
        fB0[3] = bhi((unsigned)sgB[1]) + bhi((unsigned)dgB[1]);
        fB1[0] = blo((unsigned)sgB[2]) + blo((unsigned)dgB[2]);
        fB1[1] = bhi((unsigned)sgB[2]) + bhi((unsigned)dgB[2]);
        fB1[2] = blo((unsigned)sgB[3]) + blo((unsigned)dgB[3]);
        fB1[3] = bhi((unsigned)sgB[3]) + bhi((unsigned)dgB[3]);
        int offA = pe * 68 + (pp >> 1) * 16 + (pp & 1) * 8;          // ch 8pp..
        int offB = pe * 68 + (2 + (pp >> 1)) * 16 + (pp & 1) * 8;    // ch 32+8pp..
        *(f32x4*)(gw_ + offA)     = fA0;
        *(f32x4*)(gw_ + offA + 4) = fA1;
        *(f32x4*)(gw_ + offB)     = fB0;
        *(f32x4*)(gw_ + offB + 4) = fB1;
        *(f32x4*)(ejs + pe * 20 + pp * 4) = ejr;

        // B: stage t+1 (latency hidden under this tile's compute)
        if (t < 7) {
            const short* ps = n2b + (size_t)sv[t + 1] * 64;
            const short* pd = n2b + (size_t)dv[t + 1] * 64;
            sgA = *(const i32x4*)(ps + pp * 8);
            sgB = *(const i32x4*)(ps + 32 + pp * 8);
            dgA = *(const i32x4*)(pd + pp * 8);
            dgB = *(const i32x4*)(pd + 32 + pp * 8);
            ejr = __builtin_nontemporal_load((const f32x4*)(eij + (size_t)(base + (t + 1) * 16 + pe) * 16 + pp * 4));
        }
        asm volatile("" ::: "memory");

        // C: compute tile t.  eij B-frag from LDS.
        f32x4 r0 = *(const f32x4*)(ejs + e * 20 + 8 * (g & 1));
        f32x4 r1 = *(const f32x4*)(ejs + e * 20 + 8 * (g & 1) + 4);
        i32x4 ebi;
        ebi[0] = glow ? (int)pk2(r0[0], r0[1]) : 0;
        ebi[1] = glow ? (int)pk2(r0[2], r0[3]) : 0;
        ebi[2] = glow ? (int)pk2(r1[0], r1[1]) : 0;
        ebi[3] = glow ? (int)pk2(r1[2], r1[3]) : 0;
        bf16x8 eb = __builtin_bit_cast(bf16x8, ebi);

#define L1(M)                                                                      \
        {                                                                          \
            f32x4 P = __builtin_amdgcn_mfma_f32_16x16x32_bf16(w35[M], eb, z4, 0, 0, 0); \
            f32x4 gv = *(const f32x4*)(gw_ + e * 68 + M * 16 + 4 * g);             \
            float h0 = P[0] + gv[0];                                               \
            float h1 = P[1] + gv[1];                                               \
            float h2 = P[2] + gv[2];                                               \
            float h3 = P[3] + gv[3];                                               \
            h0 = h0 > 0.f ? h0 : __expf(h0) - 1.f;                                 \
            h1 = h1 > 0.f ? h1 : __expf(h1) - 1.f;                                 \
            h2 = h2 > 0.f ? h2 : __expf(h2) - 1.f;                                 \
            h3 = h3 > 0.f ? h3 : __expf(h3) - 1.f;                                 \
            u32x2 uu; uu[0] = pk2(h0, h1); uu[1] = pk2(h2, h3);                    \
            *(u32x2*)(&hw[e * 36 + 8 * M + 2 * g]) = uu;                           \
        }
        L1(0)
        L1(1)
        L1(2)
        L1(3)
#undef L1
        asm volatile("" ::: "memory");      // hw writes before frag reads

        // hm as MFMA2 A-operand (identical read pattern as before)
        i32x4 hf0 = *(const i32x4*)(&hw[e * 36 + 4 * g]);
        i32x4 hf1 = *(const i32x4*)(&hw[e * 36 + 16 + 4 * g]);
        bf16x8 hA0 = __builtin_bit_cast(bf16x8, hf0);
        bf16x8 hA1 = __builtin_bit_cast(bf16x8, hf1);

        int tb = base + t * 16;
#define L2(M)                                                                      \
        {                                                                          \
            bf16x8 B0 = *(const bf16x8*)(sWoF + ((M * 2 + 0) * 64 + lane) * 8);    \
            bf16x8 B1 = *(const bf16x8*)(sWoF + ((M * 2 + 1) * 64 + lane) * 8);    \
            f32x4 cb = {boc[M], boc[M], boc[M], boc[M]};                           \
            f32x4 o = __builtin_amdgcn_mfma_f32_16x16x32_bf16(hA0, B0, cb, 0, 0, 0); \
            o = __builtin_amdgcn_mfma_f32_16x16x32_bf16(hA1, B1, o, 0, 0, 0);      \
            __builtin_nontemporal_store(o[0], out + (size_t)(tb + 4 * g + 0) * 64 + 16 * M + e); \
            __builtin_nontemporal_store(o[1], out + (size_t)(tb + 4 * g + 1) * 64 + 16 * M + e); \
            __builtin_nontemporal_store(o[2], out + (size_t)(tb + 4 * g + 2) * 64 + 16 * M + e); \
            __builtin_nontemporal_store(o[3], out + (size_t)(tb + 4 * g + 3) * 64 + 16 * M + e); \
        }
        L2(0)
        L2(1)
        L2(2)
        L2(3)
#undef L2
        asm volatile("" ::: "memory");      // all LDS reads done before next tile's writes
    }
}

extern "C" void kernel_launch(void* const* d_in, const int* in_sizes, int n_in,
                              void* d_out, int out_size, void* d_ws, size_t ws_size,
                              hipStream_t stream) {
    const float* h   = (const float*)d_in[0];
    const float* e   = (const float*)d_in[1];
    const float* eij = (const float*)d_in[2];
    const int*   src = (const int*)d_in[3];
    const int*   dst = (const int*)d_in[4];
    const float* W1  = (const float*)d_in[5];
    const float* b1  = (const float*)d_in[6];
    const float* W2  = (const float*)d_in[7];
    const float* b2  = (const float*)d_in[8];
    const float* W3  = (const float*)d_in[9];
    const float* b3  = (const float*)d_in[10];
    const float* Wh  = (const float*)d_in[11];
    const float* bh  = (const float*)d_in[12];
    const float* Wo  = (const float*)d_in[13];
    const float* bo  = (const float*)d_in[14];
    float* out = (float*)d_out;

    short* n2b  = (short*)d_ws;                        // 80000*64 bf16 = 10.24 MB
    short* W35F = n2b + (size_t)NNODES * 64;           // 2048 bf16 (frag order)
    short* WoF  = W35F + 2048;                         // 4096 bf16 (frag order)
    float* c    = (float*)(WoF + 4096);                // 64 f32

    hipLaunchKernelGGL(k_pre, dim3(1), dim3(1024), 0, stream, W3, b3, Wh, bh, Wo, W35F, WoF, c);
    hipLaunchKernelGGL(k_node, dim3(1000), dim3(256), 0, stream,
                       h, e, W1, b1, W2, b2, Wh, c, n2b);
    // 2500 blocks * 4 waves * 8 tiles * 16 edges = 1,280,000
    hipLaunchKernelGGL(k_edge, dim3(2500), dim3(256), 0, stream,
                       eij, src, dst, n2b, W35F, WoF, bo, out);
}

// Round 10
// 236.656 us; speedup vs baseline: 1.0891x; 1.0246x over previous
//
#include <hip/hip_runtime.h>
#include <math.h>

constexpr int NNODES = 80000;
constexpr int NEDGES = 1280000;

typedef __attribute__((ext_vector_type(8))) short bf16x8;
typedef __attribute__((ext_vector_type(4))) float f32x4;
typedef __attribute__((ext_vector_type(4))) int i32x4;
typedef __attribute__((ext_vector_type(4))) unsigned u32x4;
typedef __attribute__((ext_vector_type(2))) unsigned u32x2;

__device__ __forceinline__ short f2b(float f) {
    unsigned u = __builtin_bit_cast(unsigned, f);
    u = u + 0x7FFFu + ((u >> 16) & 1u);          // RNE to bf16
    return (short)(u >> 16);
}
__device__ __forceinline__ unsigned pk2(float lo, float hi) {
    return ((unsigned)(unsigned short)f2b(hi) << 16) | (unsigned)(unsigned short)f2b(lo);
}
__device__ __forceinline__ float blo(unsigned u) { return __builtin_bit_cast(float, u << 16); }
__device__ __forceinline__ float bhi(unsigned u) { return __builtin_bit_cast(float, u & 0xFFFF0000u); }

// K0: fold W3/b3 through Wh; emit per-lane fragments for 16x16x32 MFMA.
__global__ void k_pre(const float* __restrict__ W3, const float* __restrict__ b3,
                      const float* __restrict__ Wh, const float* __restrict__ bh,
                      const float* __restrict__ Wo,
                      short* __restrict__ W35F, short* __restrict__ WoF,
                      float* __restrict__ c) {
    int t = threadIdx.x;            // 1024 threads
#pragma unroll
    for (int r = 0; r < 2; ++r) {
        int idx = r * 1024 + t;
        int m = idx >> 9, l = (idx >> 3) & 63, i = idx & 7;
        int k = 8 * (l >> 4) + i;
        int ch = 16 * m + (l & 15);
        float s = 0.f;
        if (k < 16) {
#pragma unroll
            for (int mm = 0; mm < 64; ++mm) s += Wh[ch * 64 + mm] * W3[mm * 16 + k];
        }
        W35F[idx] = f2b(s);
    }
#pragma unroll
    for (int r = 0; r < 4; ++r) {
        int idx = r * 1024 + t;
        int f = idx >> 9, l = (idx >> 3) & 63, i = idx & 7;
        int ch = 16 * (f >> 1) + (l & 15);
        int k = 32 * (f & 1) + 8 * (l >> 4) + i;
        WoF[idx] = f2b(Wo[ch * 64 + k]);
    }
    if (t < 64) {
        float cc = bh[t];
#pragma unroll
        for (int m = 0; m < 64; ++m) cc += Wh[t * 64 + m] * b3[m];
        c[t] = cc;
    }
}

// K1: per-node  n2' = (h@W1^T + b1 + e@W2^T + b2) @ Wh^T + 0.5*c, bf16 plain rows.
__global__ __launch_bounds__(256) void k_node(
    const float* __restrict__ h, const float* __restrict__ e,
    const float* __restrict__ W1, const float* __restrict__ b1,
    const float* __restrict__ W2, const float* __restrict__ b2,
    const float* __restrict__ Wh, const float* __restrict__ c,
    short* __restrict__ n2b) {
    __shared__ float sW1T[64 * 65];
    __shared__ float sW2T[32 * 65];
    __shared__ float sWhT[64 * 65];
    __shared__ float sStage[4][160];

    int tid = threadIdx.x;
    for (int idx = tid; idx < 64 * 64; idx += 256) {
        int j = idx >> 6, k = idx & 63;
        sW1T[k * 65 + j] = W1[idx];
        sWhT[k * 65 + j] = Wh[idx];
    }
    for (int idx = tid; idx < 64 * 32; idx += 256) {
        int j = idx >> 5, k = idx & 31;
        sW2T[k * 65 + j] = W2[idx];
    }
    __syncthreads();

    int w = tid >> 6, lane = tid & 63;
    float* hs = &sStage[w][0];
    float* es = &sStage[w][64];
    float* ns = &sStage[w][96];
    int waveId = blockIdx.x * 4 + w;
    float bb = b1[lane] + b2[lane];
    float chalf = 0.5f * c[lane];

    for (int i = 0; i < 20; ++i) {
        int n = waveId * 20 + i;
        hs[lane] = h[n * 64 + lane];
        if (lane < 32) es[lane] = e[n * 32 + lane];
        float a = bb;
#pragma unroll
        for (int k = 0; k < 64; ++k) a += hs[k] * sW1T[k * 65 + lane];
#pragma unroll
        for (int k = 0; k < 32; ++k) a += es[k] * sW2T[k * 65 + lane];
        ns[lane] = a;
        float o = chalf;
#pragma unroll
        for (int k = 0; k < 64; ++k) o += ns[k] * sWhT[k * 65 + lane];
        n2b[n * 64 + lane] = f2b(o);
    }
}

// K2: ONE 16-edge tile per wave (80000 waves). Max-TLP design: no inter-tile
// chains; latency hidden by occupancy (~20 waves/CU). All global traffic
// adjacent-lane-coalesced; sg tile in bf16 (26 KB LDS/block -> 6 blocks/CU).
__global__ __launch_bounds__(256, 5) void k_edge(
    const float* __restrict__ eij, const int* __restrict__ src, const int* __restrict__ dst,
    const short* __restrict__ n2b, const short* __restrict__ W35F, const short* __restrict__ WoF,
    const float* __restrict__ bo, float* __restrict__ out) {
    __shared__ __align__(16) short sWoF[4096];        // 8 KB
    __shared__ __align__(16) unsigned sg[4][16 * 36]; // bf16-pair summed n2 rows
    __shared__ __align__(16) unsigned shw[4][16 * 36];// hm redistribution

    int tid = threadIdx.x, w = tid >> 6, lane = tid & 63;
    int e = lane & 15, g = lane >> 4;
    int pe = lane >> 2, pp = lane & 3;

    int gtile = blockIdx.x * 4 + w;          // 0..79999
    int tb = gtile * 16;

    // issue long-latency loads first
    int sv = __builtin_nontemporal_load(src + tb + pe);
    int dv = __builtin_nontemporal_load(dst + tb + pe);
    const bool glow = (g < 2);
    f32x4 ev0 = {0.f, 0.f, 0.f, 0.f}, ev1 = {0.f, 0.f, 0.f, 0.f};
    if (glow) {
        const float* ep = eij + (size_t)(tb + e) * 16 + (g & 1) * 8;
        ev0 = __builtin_nontemporal_load((const f32x4*)ep);
        ev1 = __builtin_nontemporal_load((const f32x4*)(ep + 4));
    }

    // block prologue (overlaps the loads above)
    for (int idx = tid; idx < 512; idx += 256)
        ((ulonglong2*)sWoF)[idx] = ((const ulonglong2*)WoF)[idx];

    bf16x8 w35[4];
#pragma unroll
    for (int m = 0; m < 4; ++m)
        w35[m] = *(const bf16x8*)(W35F + (m * 64 + lane) * 8);
    float boc[4];
#pragma unroll
    for (int M = 0; M < 4; ++M) boc[M] = bo[16 * M + e];
    __syncthreads();

    // gathers (depend on sv/dv): quad-contiguous 16B slices of the two node rows
    const short* ps = n2b + (size_t)sv * 64;
    const short* pd = n2b + (size_t)dv * 64;
    i32x4 sgA = *(const i32x4*)(ps + pp * 8);
    i32x4 sgB = *(const i32x4*)(ps + 32 + pp * 8);
    i32x4 dgA = *(const i32x4*)(pd + pp * 8);
    i32x4 dgB = *(const i32x4*)(pd + 32 + pp * 8);

    // sum src+dst (f32), repack to bf16 pairs, stage to LDS
    unsigned* gw_ = sg[w];
    u32x4 uA, uB;
#pragma unroll
    for (int q = 0; q < 4; ++q) {
        uA[q] = pk2(blo((unsigned)sgA[q]) + blo((unsigned)dgA[q]),
                    bhi((unsigned)sgA[q]) + bhi((unsigned)dgA[q]));
        uB[q] = pk2(blo((unsigned)sgB[q]) + blo((unsigned)dgB[q]),
                    bhi((unsigned)sgB[q]) + bhi((unsigned)dgB[q]));
    }
    *(u32x4*)(&gw_[pe * 36 + 4 * pp]) = uA;        // ch 8pp..8pp+7
    *(u32x4*)(&gw_[pe * 36 + 16 + 4 * pp]) = uB;   // ch 32+8pp..+7
    asm volatile("" ::: "memory");

    // eij B-fragment (k>=16 zero-padded on g>=2)
    i32x4 ebi;
    ebi[0] = glow ? (int)pk2(ev0[0], ev0[1]) : 0;
    ebi[1] = glow ? (int)pk2(ev0[2], ev0[3]) : 0;
    ebi[2] = glow ? (int)pk2(ev1[0], ev1[1]) : 0;
    ebi[3] = glow ? (int)pk2(ev1[2], ev1[3]) : 0;
    bf16x8 eb = __builtin_bit_cast(bf16x8, ebi);

    const f32x4 z4 = {0.f, 0.f, 0.f, 0.f};
    unsigned* hw = shw[w];
#define L1(M)                                                                      \
    {                                                                              \
        f32x4 P = __builtin_amdgcn_mfma_f32_16x16x32_bf16(w35[M], eb, z4, 0, 0, 0); \
        u32x2 rd = *(const u32x2*)(&gw_[e * 36 + 8 * M + 2 * g]);                  \
        float h0 = P[0] + blo(rd[0]);                                              \
        float h1 = P[1] + bhi(rd[0]);                                              \
        float h2 = P[2] + blo(rd[1]);                                              \
        float h3 = P[3] + bhi(rd[1]);                                              \
        h0 = h0 > 0.f ? h0 : __expf(h0) - 1.f;                                     \
        h1 = h1 > 0.f ? h1 : __expf(h1) - 1.f;                                     \
        h2 = h2 > 0.f ? h2 : __expf(h2) - 1.f;                                     \
        h3 = h3 > 0.f ? h3 : __expf(h3) - 1.f;                                     \
        u32x2 uu; uu[0] = pk2(h0, h1); uu[1] = pk2(h2, h3);                        \
        *(u32x2*)(&hw[e * 36 + 8 * M + 2 * g]) = uu;                               \
    }
    L1(0)
    L1(1)
    L1(2)
    L1(3)
#undef L1
    asm volatile("" ::: "memory");      // hw writes before frag reads

    i32x4 hf0 = *(const i32x4*)(&hw[e * 36 + 4 * g]);        // k = 8g+i
    i32x4 hf1 = *(const i32x4*)(&hw[e * 36 + 16 + 4 * g]);   // k = 32+8g+i
    bf16x8 hA0 = __builtin_bit_cast(bf16x8, hf0);
    bf16x8 hA1 = __builtin_bit_cast(bf16x8, hf1);

#define L2(M)                                                                      \
    {                                                                              \
        bf16x8 B0 = *(const bf16x8*)(sWoF + ((M * 2 + 0) * 64 + lane) * 8);        \
        bf16x8 B1 = *(const bf16x8*)(sWoF + ((M * 2 + 1) * 64 + lane) * 8);        \
        f32x4 cb = {boc[M], boc[M], boc[M], boc[M]};                               \
        f32x4 o = __builtin_amdgcn_mfma_f32_16x16x32_bf16(hA0, B0, cb, 0, 0, 0);   \
        o = __builtin_amdgcn_mfma_f32_16x16x32_bf16(hA1, B1, o, 0, 0, 0);          \
        __builtin_nontemporal_store(o[0], out + (size_t)(tb + 4 * g + 0) * 64 + 16 * M + e); \
        __builtin_nontemporal_store(o[1], out + (size_t)(tb + 4 * g + 1) * 64 + 16 * M + e); \
        __builtin_nontemporal_store(o[2], out + (size_t)(tb + 4 * g + 2) * 64 + 16 * M + e); \
        __builtin_nontemporal_store(o[3], out + (size_t)(tb + 4 * g + 3) * 64 + 16 * M + e); \
    }
    L2(0)
    L2(1)
    L2(2)
    L2(3)
#undef L2
}

extern "C" void kernel_launch(void* const* d_in, const int* in_sizes, int n_in,
                              void* d_out, int out_size, void* d_ws, size_t ws_size,
                              hipStream_t stream) {
    const float* h   = (const float*)d_in[0];
    const float* e   = (const float*)d_in[1];
    const float* eij = (const float*)d_in[2];
    const int*   src = (const int*)d_in[3];
    const int*   dst = (const int*)d_in[4];
    const float* W1  = (const float*)d_in[5];
    const float* b1  = (const float*)d_in[6];
    const float* W2  = (const float*)d_in[7];
    const float* b2  = (const float*)d_in[8];
    const float* W3  = (const float*)d_in[9];
    const float* b3  = (const float*)d_in[10];
    const float* Wh  = (const float*)d_in[11];
    const float* bh  = (const float*)d_in[12];
    const float* Wo  = (const float*)d_in[13];
    const float* bo  = (const float*)d_in[14];
    float* out = (float*)d_out;

    short* n2b  = (short*)d_ws;                        // 80000*64 bf16 = 10.24 MB
    short* W35F = n2b + (size_t)NNODES * 64;           // 2048 bf16 (frag order)
    short* WoF  = W35F + 2048;                         // 4096 bf16 (frag order)
    float* c    = (float*)(WoF + 4096);                // 64 f32

    hipLaunchKernelGGL(k_pre, dim3(1), dim3(1024), 0, stream, W3, b3, Wh, bh, Wo, W35F, WoF, c);
    hipLaunchKernelGGL(k_node, dim3(1000), dim3(256), 0, stream,
                       h, e, W1, b1, W2, b2, Wh, c, n2b);
    // 20000 blocks * 4 waves * 1 tile * 16 edges = 1,280,000
    hipLaunchKernelGGL(k_edge, dim3(20000), dim3(256), 0, stream,
                       eij, src, dst, n2b, W35F, WoF, bo, out);
}

// Round 11
// 173.450 us; speedup vs baseline: 1.4860x; 1.3644x over previous
//
#include <hip/hip_runtime.h>
#include <math.h>

constexpr int NNODES = 80000;
constexpr int NEDGES = 1280000;

typedef __attribute__((ext_vector_type(8))) short bf16x8;
typedef __attribute__((ext_vector_type(4))) float f32x4;
typedef __attribute__((ext_vector_type(4))) int i32x4;
typedef __attribute__((ext_vector_type(4))) unsigned u32x4;
typedef __attribute__((ext_vector_type(2))) unsigned u32x2;

__device__ __forceinline__ short f2b(float f) {
    unsigned u = __builtin_bit_cast(unsigned, f);
    u = u + 0x7FFFu + ((u >> 16) & 1u);          // RNE to bf16
    return (short)(u >> 16);
}
__device__ __forceinline__ unsigned pk2(float lo, float hi) {
    return ((unsigned)(unsigned short)f2b(hi) << 16) | (unsigned)(unsigned short)f2b(lo);
}
__device__ __forceinline__ float blo(unsigned u) { return __builtin_bit_cast(float, u << 16); }
__device__ __forceinline__ float bhi(unsigned u) { return __builtin_bit_cast(float, u & 0xFFFF0000u); }

// K0: emit ALL weight fragments (A-frag layout: lane l holds W[16*blk+(l&15)][8*(l>>4)+i]).
// W35F: Wh@W3 fold, K=32 (k>=16 zeroed).  WoF/W1F/WhF: 64x64, 8 frag-blocks (M,kslice).
// W2F: 64x32, 4 frag-blocks.  b12c[0..63]=b1+b2, b12c[64..127]=0.5*(bh+Wh@b3).
__global__ void k_pre(const float* __restrict__ W1, const float* __restrict__ b1,
                      const float* __restrict__ W2, const float* __restrict__ b2,
                      const float* __restrict__ W3, const float* __restrict__ b3,
                      const float* __restrict__ Wh, const float* __restrict__ bh,
                      const float* __restrict__ Wo,
                      short* __restrict__ W35F, short* __restrict__ WoF,
                      short* __restrict__ W1F, short* __restrict__ W2F,
                      short* __restrict__ WhF, float* __restrict__ b12c) {
    int t = threadIdx.x;            // 1024 threads
#pragma unroll
    for (int r = 0; r < 2; ++r) {   // W35F
        int idx = r * 1024 + t;
        int m = idx >> 9, l = (idx >> 3) & 63, i = idx & 7;
        int k = 8 * (l >> 4) + i;
        int ch = 16 * m + (l & 15);
        float s = 0.f;
        if (k < 16) {
#pragma unroll
            for (int mm = 0; mm < 64; ++mm) s += Wh[ch * 64 + mm] * W3[mm * 16 + k];
        }
        W35F[idx] = f2b(s);
    }
#pragma unroll
    for (int r = 0; r < 4; ++r) {   // WoF, W1F, WhF (64x64 each)
        int idx = r * 1024 + t;
        int blk = idx >> 9, l = (idx >> 3) & 63, i = idx & 7;
        int ch = 16 * (blk >> 1) + (l & 15);
        int k = 32 * (blk & 1) + 8 * (l >> 4) + i;
        WoF[idx] = f2b(Wo[ch * 64 + k]);
        W1F[idx] = f2b(W1[ch * 64 + k]);
        WhF[idx] = f2b(Wh[ch * 64 + k]);
    }
#pragma unroll
    for (int r = 0; r < 2; ++r) {   // W2F (64x32)
        int idx = r * 1024 + t;
        int M = idx >> 9, l = (idx >> 3) & 63, i = idx & 7;
        int ch = 16 * M + (l & 15);
        int k = 8 * (l >> 4) + i;
        W2F[idx] = f2b(W2[ch * 32 + k]);
    }
    if (t < 64) {
        b12c[t] = b1[t] + b2[t];
        float cc = bh[t];
#pragma unroll
        for (int m = 0; m < 64; ++m) cc += Wh[t * 64 + m] * b3[m];
        b12c[64 + t] = 0.5f * cc;
    }
}

// K1 (MFMA): per 16-node tile, lane=(e=node,g):
//  stage1: acc_M = W1F@Bh + W2F@Be + b12      (12 MFMA, B-frags direct from global)
//  redistribute bf16 via per-wave LDS (same pattern as k_edge)
//  stage2: n2' = WhF@npn^T + 0.5c             (8 MFMA), write bf16 rows.
__global__ __launch_bounds__(256, 4) void k_node(
    const float* __restrict__ h, const float* __restrict__ ein,
    const short* __restrict__ W1F, const short* __restrict__ W2F,
    const short* __restrict__ WhF, const float* __restrict__ b12c,
    short* __restrict__ n2b) {
    __shared__ __align__(16) unsigned shw[4][16 * 36];

    int tid = threadIdx.x, w = tid >> 6, lane = tid & 63;
    int e = lane & 15, g = lane >> 4;
    int node = (blockIdx.x * 4 + w) * 16 + e;

    // B-frags straight from global rows (lane reads its own 32B chunk)
    const float* hp = h + (size_t)node * 64;
    f32x4 h00 = *(const f32x4*)(hp + 8 * g);
    f32x4 h01 = *(const f32x4*)(hp + 8 * g + 4);
    f32x4 h10 = *(const f32x4*)(hp + 32 + 8 * g);
    f32x4 h11 = *(const f32x4*)(hp + 32 + 8 * g + 4);
    const float* ep = ein + (size_t)node * 32;
    f32x4 e0 = *(const f32x4*)(ep + 8 * g);
    f32x4 e1 = *(const f32x4*)(ep + 8 * g + 4);

    i32x4 u0, u1, u2;
    u0[0] = (int)pk2(h00[0], h00[1]); u0[1] = (int)pk2(h00[2], h00[3]);
    u0[2] = (int)pk2(h01[0], h01[1]); u0[3] = (int)pk2(h01[2], h01[3]);
    u1[0] = (int)pk2(h10[0], h10[1]); u1[1] = (int)pk2(h10[2], h10[3]);
    u1[2] = (int)pk2(h11[0], h11[1]); u1[3] = (int)pk2(h11[2], h11[3]);
    u2[0] = (int)pk2(e0[0], e0[1]);   u2[1] = (int)pk2(e0[2], e0[3]);
    u2[2] = (int)pk2(e1[0], e1[1]);   u2[3] = (int)pk2(e1[2], e1[3]);
    bf16x8 Bh0 = __builtin_bit_cast(bf16x8, u0);
    bf16x8 Bh1 = __builtin_bit_cast(bf16x8, u1);
    bf16x8 Be  = __builtin_bit_cast(bf16x8, u2);

    unsigned* hw = shw[w];
#pragma unroll
    for (int M = 0; M < 4; ++M) {
        bf16x8 A0 = *(const bf16x8*)(W1F + ((M * 2 + 0) * 64 + lane) * 8);
        bf16x8 A1 = *(const bf16x8*)(W1F + ((M * 2 + 1) * 64 + lane) * 8);
        bf16x8 A2 = *(const bf16x8*)(W2F + (M * 64 + lane) * 8);
        f32x4 cb = *(const f32x4*)(b12c + 16 * M + 4 * g);
        f32x4 acc = __builtin_amdgcn_mfma_f32_16x16x32_bf16(A0, Bh0, cb, 0, 0, 0);
        acc = __builtin_amdgcn_mfma_f32_16x16x32_bf16(A1, Bh1, acc, 0, 0, 0);
        acc = __builtin_amdgcn_mfma_f32_16x16x32_bf16(A2, Be, acc, 0, 0, 0);
        u32x2 uu; uu[0] = pk2(acc[0], acc[1]); uu[1] = pk2(acc[2], acc[3]);
        *(u32x2*)(&hw[e * 36 + 8 * M + 2 * g]) = uu;
    }
    asm volatile("" ::: "memory");

    i32x4 hf0 = *(const i32x4*)(&hw[e * 36 + 4 * g]);        // k = 8g+i
    i32x4 hf1 = *(const i32x4*)(&hw[e * 36 + 16 + 4 * g]);   // k = 32+8g+i
    bf16x8 B0 = __builtin_bit_cast(bf16x8, hf0);
    bf16x8 B1 = __builtin_bit_cast(bf16x8, hf1);

#pragma unroll
    for (int M = 0; M < 4; ++M) {
        bf16x8 A0 = *(const bf16x8*)(WhF + ((M * 2 + 0) * 64 + lane) * 8);
        bf16x8 A1 = *(const bf16x8*)(WhF + ((M * 2 + 1) * 64 + lane) * 8);
        f32x4 cc = *(const f32x4*)(b12c + 64 + 16 * M + 4 * g);
        f32x4 o = __builtin_amdgcn_mfma_f32_16x16x32_bf16(A0, B0, cc, 0, 0, 0);
        o = __builtin_amdgcn_mfma_f32_16x16x32_bf16(A1, B1, o, 0, 0, 0);
        u32x2 uu; uu[0] = pk2(o[0], o[1]); uu[1] = pk2(o[2], o[3]);
        *(u32x2*)(n2b + (size_t)node * 64 + 16 * M + 4 * g) = uu;
    }
}

// K2: ONE 16-edge tile per wave (80000 waves) — unchanged from R10.
__global__ __launch_bounds__(256, 5) void k_edge(
    const float* __restrict__ eij, const int* __restrict__ src, const int* __restrict__ dst,
    const short* __restrict__ n2b, const short* __restrict__ W35F, const short* __restrict__ WoF,
    const float* __restrict__ bo, float* __restrict__ out) {
    __shared__ __align__(16) short sWoF[4096];        // 8 KB
    __shared__ __align__(16) unsigned sg[4][16 * 36]; // bf16-pair summed n2 rows
    __shared__ __align__(16) unsigned shw[4][16 * 36];// hm redistribution

    int tid = threadIdx.x, w = tid >> 6, lane = tid & 63;
    int e = lane & 15, g = lane >> 4;
    int pe = lane >> 2, pp = lane & 3;

    int gtile = blockIdx.x * 4 + w;          // 0..79999
    int tb = gtile * 16;

    int sv = __builtin_nontemporal_load(src + tb + pe);
    int dv = __builtin_nontemporal_load(dst + tb + pe);
    const bool glow = (g < 2);
    f32x4 ev0 = {0.f, 0.f, 0.f, 0.f}, ev1 = {0.f, 0.f, 0.f, 0.f};
    if (glow) {
        const float* ep = eij + (size_t)(tb + e) * 16 + (g & 1) * 8;
        ev0 = __builtin_nontemporal_load((const f32x4*)ep);
        ev1 = __builtin_nontemporal_load((const f32x4*)(ep + 4));
    }

    for (int idx = tid; idx < 512; idx += 256)
        ((ulonglong2*)sWoF)[idx] = ((const ulonglong2*)WoF)[idx];

    bf16x8 w35[4];
#pragma unroll
    for (int m = 0; m < 4; ++m)
        w35[m] = *(const bf16x8*)(W35F + (m * 64 + lane) * 8);
    float boc[4];
#pragma unroll
    for (int M = 0; M < 4; ++M) boc[M] = bo[16 * M + e];
    __syncthreads();

    const short* ps = n2b + (size_t)sv * 64;
    const short* pd = n2b + (size_t)dv * 64;
    i32x4 sgA = *(const i32x4*)(ps + pp * 8);
    i32x4 sgB = *(const i32x4*)(ps + 32 + pp * 8);
    i32x4 dgA = *(const i32x4*)(pd + pp * 8);
    i32x4 dgB = *(const i32x4*)(pd + 32 + pp * 8);

    unsigned* gw_ = sg[w];
    u32x4 uA, uB;
#pragma unroll
    for (int q = 0; q < 4; ++q) {
        uA[q] = pk2(blo((unsigned)sgA[q]) + blo((unsigned)dgA[q]),
                    bhi((unsigned)sgA[q]) + bhi((unsigned)dgA[q]));
        uB[q] = pk2(blo((unsigned)sgB[q]) + blo((unsigned)dgB[q]),
                    bhi((unsigned)sgB[q]) + bhi((unsigned)dgB[q]));
    }
    *(u32x4*)(&gw_[pe * 36 + 4 * pp]) = uA;
    *(u32x4*)(&gw_[pe * 36 + 16 + 4 * pp]) = uB;
    asm volatile("" ::: "memory");

    i32x4 ebi;
    ebi[0] = glow ? (int)pk2(ev0[0], ev0[1]) : 0;
    ebi[1] = glow ? (int)pk2(ev0[2], ev0[3]) : 0;
    ebi[2] = glow ? (int)pk2(ev1[0], ev1[1]) : 0;
    ebi[3] = glow ? (int)pk2(ev1[2], ev1[3]) : 0;
    bf16x8 eb = __builtin_bit_cast(bf16x8, ebi);

    const f32x4 z4 = {0.f, 0.f, 0.f, 0.f};
    unsigned* hw = shw[w];
#define L1(M)                                                                      \
    {                                                                              \
        f32x4 P = __builtin_amdgcn_mfma_f32_16x16x32_bf16(w35[M], eb, z4, 0, 0, 0); \
        u32x2 rd = *(const u32x2*)(&gw_[e * 36 + 8 * M + 2 * g]);                  \
        float h0 = P[0] + blo(rd[0]);                                              \
        float h1 = P[1] + bhi(rd[0]);                                              \
        float h2 = P[2] + blo(rd[1]);                                              \
        float h3 = P[3] + bhi(rd[1]);                                              \
        h0 = h0 > 0.f ? h0 : __expf(h0) - 1.f;                                     \
        h1 = h1 > 0.f ? h1 : __expf(h1) - 1.f;                                     \
        h2 = h2 > 0.f ? h2 : __expf(h2) - 1.f;                                     \
        h3 = h3 > 0.f ? h3 : __expf(h3) - 1.f;                                     \
        u32x2 uu; uu[0] = pk2(h0, h1); uu[1] = pk2(h2, h3);                        \
        *(u32x2*)(&hw[e * 36 + 8 * M + 2 * g]) = uu;                               \
    }
    L1(0)
    L1(1)
    L1(2)
    L1(3)
#undef L1
    asm volatile("" ::: "memory");

    i32x4 hf0 = *(const i32x4*)(&hw[e * 36 + 4 * g]);
    i32x4 hf1 = *(const i32x4*)(&hw[e * 36 + 16 + 4 * g]);
    bf16x8 hA0 = __builtin_bit_cast(bf16x8, hf0);
    bf16x8 hA1 = __builtin_bit_cast(bf16x8, hf1);

#define L2(M)                                                                      \
    {                                                                              \
        bf16x8 B0 = *(const bf16x8*)(sWoF + ((M * 2 + 0) * 64 + lane) * 8);        \
        bf16x8 B1 = *(const bf16x8*)(sWoF + ((M * 2 + 1) * 64 + lane) * 8);        \
        f32x4 cb = {boc[M], boc[M], boc[M], boc[M]};                               \
        f32x4 o = __builtin_amdgcn_mfma_f32_16x16x32_bf16(hA0, B0, cb, 0, 0, 0);   \
        o = __builtin_amdgcn_mfma_f32_16x16x32_bf16(hA1, B1, o, 0, 0, 0);          \
        __builtin_nontemporal_store(o[0], out + (size_t)(tb + 4 * g + 0) * 64 + 16 * M + e); \
        __builtin_nontemporal_store(o[1], out + (size_t)(tb + 4 * g + 1) * 64 + 16 * M + e); \
        __builtin_nontemporal_store(o[2], out + (size_t)(tb + 4 * g + 2) * 64 + 16 * M + e); \
        __builtin_nontemporal_store(o[3], out + (size_t)(tb + 4 * g + 3) * 64 + 16 * M + e); \
    }
    L2(0)
    L2(1)
    L2(2)
    L2(3)
#undef L2
}

extern "C" void kernel_launch(void* const* d_in, const int* in_sizes, int n_in,
                              void* d_out, int out_size, void* d_ws, size_t ws_size,
                              hipStream_t stream) {
    const float* h   = (const float*)d_in[0];
    const float* e   = (const float*)d_in[1];
    const float* eij = (const float*)d_in[2];
    const int*   src = (const int*)d_in[3];
    const int*   dst = (const int*)d_in[4];
    const float* W1  = (const float*)d_in[5];
    const float* b1  = (const float*)d_in[6];
    const float* W2  = (const float*)d_in[7];
    const float* b2  = (const float*)d_in[8];
    const float* W3  = (const float*)d_in[9];
    const float* b3  = (const float*)d_in[10];
    const float* Wh  = (const float*)d_in[11];
    const float* bh  = (const float*)d_in[12];
    const float* Wo  = (const float*)d_in[13];
    const float* bo  = (const float*)d_in[14];
    float* out = (float*)d_out;

    short* n2b  = (short*)d_ws;                        // 80000*64 bf16 = 10.24 MB
    short* W35F = n2b + (size_t)NNODES * 64;           // 2048
    short* WoF  = W35F + 2048;                         // 4096
    short* W1F  = WoF + 4096;                          // 4096
    short* W2F  = W1F + 4096;                          // 2048
    short* WhF  = W2F + 2048;                          // 4096
    float* b12c = (float*)(WhF + 4096);                // 128 f32

    hipLaunchKernelGGL(k_pre, dim3(1), dim3(1024), 0, stream,
                       W1, b1, W2, b2, W3, b3, Wh, bh, Wo,
                       W35F, WoF, W1F, W2F, WhF, b12c);
    // 1250 blocks * 4 waves * 16 nodes = 80,000
    hipLaunchKernelGGL(k_node, dim3(1250), dim3(256), 0, stream,
                       h, e, W1F, W2F, WhF, b12c, n2b);
    // 20000 blocks * 4 waves * 1 tile * 16 edges = 1,280,000
    hipLaunchKernelGGL(k_edge, dim3(20000), dim3(256), 0, stream,
                       eij, src, dst, n2b, W35F, WoF, bo, out);
}